// Round 6
// baseline (494.784 us; speedup 1.0000x reference)
//
#include <hip/hip_runtime.h>
#include <math.h>

// ProbSparse attention (Informer). B=2 L=4096 H=8 D=64, U_part=u=45.
// R13: pipeline fused 4 kernels -> 2 via split-k "last block per bh
// finishes" (device-scope atomicAdd + __threadfence, cross-XCD-safe).
//  A = scoreM (R12 internals) + per-bh topk finisher (overlaps scoreM tail)
//  B = attn (R12 internals) + per-bh merge finisher (wave-per-t, no LDS)
// Rationale: 165.9 total - 43 scoreM - 41.5 harness-fill - ~12 attn/merge
// leaves ~50-60us in k_topk (16 blocks, ~80 syncs, pass-1 LDS-atomic
// contention ~2000-way: normal M values collapse to 2-3 exponent buckets)
// + ~10us/kernel launch gaps. Fusion attacks both AND makes topk/attn
// costs visible: durA-43 = topk, durB-attn = merge.
// Predict: durA 55-62us; total 142-152 if gap theory holds, else ~165
// (neutral) with measurement gained. Counters zeroed by 128-B memsetAsync.
#define JAX_PARTITIONABLE 1

constexpr int Bc = 2, Lc = 4096, Hc = 8, Dc = 64;
constexpr int BHc = Bc * Hc;     // 16
constexpr int Uc = 45;           // top-k queries
constexpr int NSc = 45;          // samples per query

typedef float vfloat4 __attribute__((ext_vector_type(4)));

struct TF2 { unsigned a, b; };

__host__ __device__ constexpr unsigned rotl32(unsigned v, int n) {
  return (v << n) | (v >> (32 - n));
}

// Threefry-2x32, 20 rounds (JAX reference schedule).
__host__ __device__ constexpr TF2 tf2(unsigned k0, unsigned k1, unsigned x0, unsigned x1) {
  unsigned ks2 = k0 ^ k1 ^ 0x1BD11BDAu;
  x0 += k0; x1 += k1;
  x0 += x1; x1 = rotl32(x1, 13); x1 ^= x0;
  x0 += x1; x1 = rotl32(x1, 15); x1 ^= x0;
  x0 += x1; x1 = rotl32(x1, 26); x1 ^= x0;
  x0 += x1; x1 = rotl32(x1, 6);  x1 ^= x0;
  x0 += k1; x1 += ks2 + 1u;
  x0 += x1; x1 = rotl32(x1, 17); x1 ^= x0;
  x0 += x1; x1 = rotl32(x1, 29); x1 ^= x0;
  x0 += x1; x1 = rotl32(x1, 16); x1 ^= x0;
  x0 += x1; x1 = rotl32(x1, 24); x1 ^= x0;
  x0 += ks2; x1 += k0 + 2u;
  x0 += x1; x1 = rotl32(x1, 13); x1 ^= x0;
  x0 += x1; x1 = rotl32(x1, 15); x1 ^= x0;
  x0 += x1; x1 = rotl32(x1, 26); x1 ^= x0;
  x0 += x1; x1 = rotl32(x1, 6);  x1 ^= x0;
  x0 += k0; x1 += k1 + 3u;
  x0 += x1; x1 = rotl32(x1, 17); x1 ^= x0;
  x0 += x1; x1 = rotl32(x1, 29); x1 ^= x0;
  x0 += x1; x1 = rotl32(x1, 16); x1 ^= x0;
  x0 += x1; x1 = rotl32(x1, 24); x1 ^= x0;
  x0 += k1; x1 += ks2 + 4u;
  x0 += x1; x1 = rotl32(x1, 13); x1 ^= x0;
  x0 += x1; x1 = rotl32(x1, 15); x1 ^= x0;
  x0 += x1; x1 = rotl32(x1, 26); x1 ^= x0;
  x0 += x1; x1 = rotl32(x1, 6);  x1 ^= x0;
  x0 += ks2; x1 += k0 + 5u;
  return TF2{x0, x1};
}

// VALU-pipe partial-sum add via DPP (identity old=0 for invalid lanes).
template <int CTRL>
__device__ __forceinline__ float dpp_add(float x) {
  int t = __builtin_amdgcn_update_dpp(0, __float_as_int(x), CTRL, 0xF, 0xF, false);
  return x + __int_as_float(t);
}
// DPP-shifted value with own value as identity for invalid lanes (for max).
template <int CTRL>
__device__ __forceinline__ float dpp_idf(float x) {
  int t = __builtin_amdgcn_update_dpp(__float_as_int(x), __float_as_int(x), CTRL, 0xF, 0xF, false);
  return __int_as_float(t);
}
// Full-wave (64-lane) max/sum: result valid at lane 63, broadcast via readlane.
__device__ __forceinline__ float wave_max_bcast(float x) {
  x = fmaxf(x, dpp_idf<0x111>(x));   // row_shr:1
  x = fmaxf(x, dpp_idf<0x112>(x));   // row_shr:2
  x = fmaxf(x, dpp_idf<0x114>(x));   // row_shr:4
  x = fmaxf(x, dpp_idf<0x118>(x));   // row_shr:8  -> lane15 of each row = row max
  x = fmaxf(x, dpp_idf<0x142>(x));   // row_bcast:15
  x = fmaxf(x, dpp_idf<0x143>(x));   // row_bcast:31 -> lane63 = wave max
  return __int_as_float(__builtin_amdgcn_readlane(__float_as_int(x), 63));
}
__device__ __forceinline__ float wave_sum_bcast(float x) {
  x = dpp_add<0x111>(x);
  x = dpp_add<0x112>(x);
  x = dpp_add<0x114>(x);
  x = dpp_add<0x118>(x);
  x = dpp_add<0x142>(x);
  x = dpp_add<0x143>(x);
  return __int_as_float(__builtin_amdgcn_readlane(__float_as_int(x), 63));
}

// fmaf chain for a float4 dot accumulated into a: 4 VALU insts.
__device__ __forceinline__ float dot4_acc(float4 q, float4 k, float a) {
  a = fmaf(q.x, k.x, a);
  a = fmaf(q.y, k.y, a);
  a = fmaf(q.z, k.z, a);
  a = fmaf(q.w, k.w, a);
  return a;
}

// LDS layout for kernel A: scoreM phase uses sidx; topk finisher reuses the
// same LDS as the (larger) TopkSh block. Union keeps the block size at the
// topk requirement (~19 KB; 8 blocks/CU still >= the 32-wave cap).
struct TopkSh {
  unsigned su[Lc];     // 16 KB mapped keys
  int hist[256];
  int sfx[257];
  unsigned s_prefix;
  int s_r;
  int n_gt, n_eq;
  unsigned cu[64];
  int cidx[64];
  int eqi[64];
  int srank[Uc];
};
union ShA {
  int sidx[720];
  TopkSh tk;
};

// Kernel A: scoreM (R12-identical internals) + per-bh topk finisher.
// M[bh][q] = max_s dot(Q[q],K[idx[q][s]]) - sum_s(...)/4096.
// bh = blockIdx&15 keeps 2-bh-per-XCD K/Q L2 residency. The 256th block of a
// bh to finish (device-scope counter) runs the exact radix-select top-45 +
// Q pre-gather for that bh, overlapping other bh's scoreM tail.
__global__ __launch_bounds__(256) void k_scoreM_topk(const float* __restrict__ Q,
                                                     const float* __restrict__ K,
                                                     float* __restrict__ M,
                                                     int* __restrict__ cnt,
                                                     int* __restrict__ topk,
                                                     float* __restrict__ qg) {
  __shared__ ShA sh;
  __shared__ int s_go;
  int tid = threadIdx.x;
  int bx = blockIdx.x;
  int bh = bx & 15;
  int qblk = bx >> 4;              // 0..255
  int b = bh >> 3, h = bh & 7;
  int lane16 = tid & 15, qloc = tid >> 4;
  int q = qblk * 16 + qloc;
  constexpr TF2 kb = tf2(0u, 1u, 0u, 1u);
  for (int e = tid; e < 720; e += 256) {
    TF2 r = tf2(kb.a, kb.b, 0u, (unsigned)(qblk * 720 + e));
    sh.sidx[e] = (int)((r.a ^ r.b) & 4095u);
  }
  __syncthreads();
  {
    const vfloat4* Q4 = (const vfloat4*)Q;
    const vfloat4* K4 = (const vfloat4*)K;
    vfloat4 qr = Q4[((b * Lc + q) * Hc + h) * 16 + lane16];
    int kbase = (b * Lc * Hc + h) * 16 + lane16;
    const int* ip = sh.sidx + qloc * NSc;
    float mx = -INFINITY, sm = 0.f;
    #pragma unroll
    for (int s0 = 0; s0 < NSc; s0 += 5) {      // 5-deep load batch: L2 loads in flight
      int kk[5];
      #pragma unroll
      for (int i = 0; i < 5; ++i) kk[i] = ip[s0 + i];
      vfloat4 kv[5];
      #pragma unroll
      for (int i = 0; i < 5; ++i) kv[i] = __builtin_nontemporal_load(&K4[kbase + kk[i] * (Hc * 16)]);
      #pragma unroll
      for (int i = 0; i < 5; ++i) {
        float p = fmaf(qr[0], kv[i][0], fmaf(qr[1], kv[i][1], fmaf(qr[2], kv[i][2], qr[3] * kv[i][3])));
        p = dpp_add<0x111>(p);                 // row_shr cascade -> lane15 = full dot
        p = dpp_add<0x112>(p);
        p = dpp_add<0x114>(p);
        p = dpp_add<0x118>(p);
        mx = fmaxf(mx, p);                     // valid at lane15; junk elsewhere (never read)
        sm += p;
      }
    }
    if (lane16 == 15) M[bh * Lc + q] = mx - sm * (1.0f / Lc);
  }
  // ---- split-k completion: last block of this bh runs topk ----
  __syncthreads();                 // all M stores issued + vmcnt drained
  if (tid == 0) {
    __threadfence();               // device-scope release: flush this XCD's L2
    int old = atomicAdd(&cnt[bh], 1);
    s_go = (old == 255) ? 1 : 0;
  }
  __syncthreads();
  if (!s_go) return;
  if (tid == 0) __threadfence();   // acquire: invalidate stale cached lines
  __syncthreads();

  // ---- exact lax.top_k radix select (R12 k_topk body, bh fixed) ----
  const float* m = M + bh * Lc;
  for (int e = tid; e < Lc; e += 256) {
    unsigned bb = __float_as_uint(m[e]);
    sh.tk.su[e] = (bb & 0x80000000u) ? ~bb : (bb | 0x80000000u);
  }
  if (tid == 0) { sh.tk.s_r = Uc; sh.tk.s_prefix = 0u; sh.tk.n_gt = 0; sh.tk.n_eq = 0; }
  __syncthreads();
  #pragma unroll
  for (int p = 0; p < 4; ++p) {
    int shift = 24 - 8 * p;
    sh.tk.hist[tid] = 0;
    __syncthreads();
    unsigned pref = sh.tk.s_prefix;
    unsigned hmask = (p == 0) ? 0u : (0xFFFFFFFFu << (shift + 8));
    for (int e = tid; e < Lc; e += 256) {
      unsigned u = sh.tk.su[e];
      if ((u & hmask) == pref) atomicAdd(&sh.tk.hist[(u >> shift) & 255u], 1);
    }
    __syncthreads();
    sh.tk.sfx[tid] = sh.tk.hist[tid];
    __syncthreads();
    for (int off = 1; off < 256; off <<= 1) {   // inclusive suffix sum
      int v = (tid + off < 256) ? sh.tk.sfx[tid + off] : 0;
      __syncthreads();
      sh.tk.sfx[tid] += v;
      __syncthreads();
    }
    int r = sh.tk.s_r;
    __syncthreads();                            // all read s_r before update
    int above = (tid < 255) ? sh.tk.sfx[tid + 1] : 0;
    if (sh.tk.sfx[tid] >= r && above < r) {     // unique digit
      sh.tk.s_r = r - above;
      sh.tk.s_prefix = pref | ((unsigned)tid << shift);
    }
    __syncthreads();
  }
  unsigned T = sh.tk.s_prefix;                  // exact 45th-largest key
  int rf = sh.tk.s_r;                           // #equals to take (>=1)
  for (int e = tid; e < Lc; e += 256) {
    unsigned u = sh.tk.su[e];
    if (u > T) {
      int p = atomicAdd(&sh.tk.n_gt, 1);        // <= 44
      sh.tk.cu[p] = u; sh.tk.cidx[p] = e;
    } else if (u == T) {
      int p = atomicAdd(&sh.tk.n_eq, 1);
      if (p < 64) sh.tk.eqi[p] = e;             // >64-way ties: impossible for random-normal M
    }
  }
  __syncthreads();
  int ne = sh.tk.n_eq < 64 ? sh.tk.n_eq : 64;
  if (tid < ne) {
    int myi = sh.tk.eqi[tid];
    int rank = 0;
    for (int j = 0; j < ne; ++j) rank += (sh.tk.eqi[j] < myi);
    if (rank < rf) {
      int p = atomicAdd(&sh.tk.n_gt, 1);        // completes to exactly 45
      sh.tk.cu[p] = T; sh.tk.cidx[p] = myi;
    }
  }
  __syncthreads();
  if (tid < Uc) {
    unsigned mu = sh.tk.cu[tid]; int mi = sh.tk.cidx[tid];
    int rank = 0;
    for (int j = 0; j < Uc; ++j) {
      unsigned ju = sh.tk.cu[j]; int ji = sh.tk.cidx[j];
      rank += (ju > mu) || (ju == mu && ji < mi);
    }
    topk[bh * Uc + rank] = mi;
    sh.tk.srank[rank] = mi;
  }
  __syncthreads();
  const float4* Q4 = (const float4*)Q;
  float4* qg4 = (float4*)qg;
  for (int e = tid; e < Uc * 16; e += 256) {    // coalesced pre-gather of selected Q rows
    int t = e >> 4, dq = e & 15;
    qg4[bh * Uc * 16 + e] = Q4[((b * Lc + sh.tk.srank[t]) * Hc + h) * 16 + dq];
  }
}

// Kernel B: flash-decoding partials (R12 k_attn internals) + per-bh merge
// finisher. One block per (bh, CH-key chunk), CH = 4096/NC. The NC'th block
// of a bh to finish merges all chunk partials for that bh (wave w handles
// t = w, w+4, ...; lane = output dim d; pM/pL loads wave-uniform -> scalar).
template<int NC>
__global__ __launch_bounds__(256) void k_attn_merge(const float* __restrict__ qg, const float* __restrict__ K,
                                                    const float* __restrict__ V, const int* __restrict__ amask,
                                                    float* __restrict__ pO, float* __restrict__ pM,
                                                    float* __restrict__ pL, int* __restrict__ cnt,
                                                    float* __restrict__ out) {
  constexpr int CH = Lc / NC;
  constexpr int TG = 256 / CH;
  constexpr int SCW = CH + 4;      // row stride 68 floats = 272 B (16-B aligned rows)
  int chunk = blockIdx.x, bh = blockIdx.y;
  int b = bh >> 3, h = bh & 7;
  int tid = threadIdx.x;
  __shared__ __align__(16) float qs[Uc * 64];
  __shared__ __align__(16) float sc[48][SCW];
  __shared__ int s_go;
  {
    const float4* qg4 = (const float4*)qg;
    float4* qs4w = (float4*)qs;
    for (int e = tid; e < Uc * 16; e += 256) qs4w[e] = qg4[bh * Uc * 16 + e];
  }
  for (int e = tid; e < 3 * SCW; e += 256) sc[45 + e / SCW][e % SCW] = 0.f;
  __syncthreads();
  {
    int k = tid % CH, tg = tid / CH;
    int key = chunk * CH + k;
    const float4* K4 = (const float4*)K;
    int kb = ((b * Lc + key) * Hc + h) * 16;
    float4 kr[16];
    #pragma unroll
    for (int j = 0; j < 16; ++j) kr[j] = K4[kb + j];
    int mk = amask[b * Lc + key];
    const float4* qs4 = (const float4*)qs;
    for (int t = tg; t < Uc; t += TG) {
      float a0 = 0.f, a1 = 0.f, a2 = 0.f, a3 = 0.f;   // 4 independent fmaf chains
      #pragma unroll
      for (int j = 0; j < 16; j += 4) {
        a0 = dot4_acc(qs4[t * 16 + j],     kr[j],     a0);
        a1 = dot4_acc(qs4[t * 16 + j + 1], kr[j + 1], a1);
        a2 = dot4_acc(qs4[t * 16 + j + 2], kr[j + 2], a2);
        a3 = dot4_acc(qs4[t * 16 + j + 3], kr[j + 3], a3);
      }
      float acc = (a0 + a1) + (a2 + a3);
      sc[t][k] = mk ? acc * 0.125f : -INFINITY;
    }
  }
  __syncthreads();
  {
    // CH=64: one wave per score row; DPP reductions (VALU pipe).
    int w = tid >> 6, lane = tid & 63;
    for (int t = w; t < Uc; t += 4) {
      float x = sc[t][lane];
      float ml = wave_max_bcast(x);
      float p = (ml != -INFINITY) ? __expf(x - ml) : 0.f;   // fully-masked chunk guard
      sc[t][lane] = p;
      float ls = wave_sum_bcast(p);
      if (lane == 0) {
        pM[(bh * NC + chunk) * Uc + t] = ml;
        pL[(bh * NC + chunk) * Uc + t] = ls;
      }
    }
  }
  __syncthreads();
  {
    int ty = tid >> 4, tx = tid & 15;
    float4 o0 = {0.f, 0.f, 0.f, 0.f};
    float4 o1 = {0.f, 0.f, 0.f, 0.f};
    float4 o2 = {0.f, 0.f, 0.f, 0.f};
    const float4* V4 = (const float4*)V;
    const float4* s0 = (const float4*)&sc[ty][0];        // rows 16-B aligned (SCW=68)
    const float4* s1 = (const float4*)&sc[ty + 16][0];
    const float4* s2 = (const float4*)&sc[ty + 32][0];
    int vbase = (b * Lc + chunk * CH) * (Hc * 16) + h * 16 + tx;
    #pragma unroll 2
    for (int kq = 0; kq < CH / 4; ++kq) {
      float4 p0 = s0[kq], p1 = s1[kq], p2 = s2[kq];      // 4 keys per ds_read_b128
      float4 va = V4[vbase + (4 * kq + 0) * (Hc * 16)];
      float4 vb = V4[vbase + (4 * kq + 1) * (Hc * 16)];
      float4 vc = V4[vbase + (4 * kq + 2) * (Hc * 16)];
      float4 vd = V4[vbase + (4 * kq + 3) * (Hc * 16)];
      o0.x = fmaf(p0.x, va.x, o0.x); o0.y = fmaf(p0.x, va.y, o0.y); o0.z = fmaf(p0.x, va.z, o0.z); o0.w = fmaf(p0.x, va.w, o0.w);
      o1.x = fmaf(p1.x, va.x, o1.x); o1.y = fmaf(p1.x, va.y, o1.y); o1.z = fmaf(p1.x, va.z, o1.z); o1.w = fmaf(p1.x, va.w, o1.w);
      o2.x = fmaf(p2.x, va.x, o2.x); o2.y = fmaf(p2.x, va.y, o2.y); o2.z = fmaf(p2.x, va.z, o2.z); o2.w = fmaf(p2.x, va.w, o2.w);
      o0.x = fmaf(p0.y, vb.x, o0.x); o0.y = fmaf(p0.y, vb.y, o0.y); o0.z = fmaf(p0.y, vb.z, o0.z); o0.w = fmaf(p0.y, vb.w, o0.w);
      o1.x = fmaf(p1.y, vb.x, o1.x); o1.y = fmaf(p1.y, vb.y, o1.y); o1.z = fmaf(p1.y, vb.z, o1.z); o1.w = fmaf(p1.y, vb.w, o1.w);
      o2.x = fmaf(p2.y, vb.x, o2.x); o2.y = fmaf(p2.y, vb.y, o2.y); o2.z = fmaf(p2.y, vb.z, o2.z); o2.w = fmaf(p2.y, vb.w, o2.w);
      o0.x = fmaf(p0.z, vc.x, o0.x); o0.y = fmaf(p0.z, vc.y, o0.y); o0.z = fmaf(p0.z, vc.z, o0.z); o0.w = fmaf(p0.z, vc.w, o0.w);
      o1.x = fmaf(p1.z, vc.x, o1.x); o1.y = fmaf(p1.z, vc.y, o1.y); o1.z = fmaf(p1.z, vc.z, o1.z); o1.w = fmaf(p1.z, vc.w, o1.w);
      o2.x = fmaf(p2.z, vc.x, o2.x); o2.y = fmaf(p2.z, vc.y, o2.y); o2.z = fmaf(p2.z, vc.z, o2.z); o2.w = fmaf(p2.z, vc.w, o2.w);
      o0.x = fmaf(p0.w, vd.x, o0.x); o0.y = fmaf(p0.w, vd.y, o0.y); o0.z = fmaf(p0.w, vd.z, o0.z); o0.w = fmaf(p0.w, vd.w, o0.w);
      o1.x = fmaf(p1.w, vd.x, o1.x); o1.y = fmaf(p1.w, vd.y, o1.y); o1.z = fmaf(p1.w, vd.z, o1.z); o1.w = fmaf(p1.w, vd.w, o1.w);
      o2.x = fmaf(p2.w, vd.x, o2.x); o2.y = fmaf(p2.w, vd.y, o2.y); o2.z = fmaf(p2.w, vd.z, o2.z); o2.w = fmaf(p2.w, vd.w, o2.w);
    }
    float4* pO4 = (float4*)pO;
    int obase = ((bh * NC + chunk) * Uc) * 16 + tx;
    pO4[obase + ty * 16] = o0;
    pO4[obase + (ty + 16) * 16] = o1;
    if (ty < 13) pO4[obase + (ty + 32) * 16] = o2;
  }
  // ---- split-k completion: last chunk block of this bh merges ----
  __syncthreads();                 // all pO/pM/pL stores issued + drained
  if (tid == 0) {
    __threadfence();               // device-scope release
    int old = atomicAdd(&cnt[bh], 1);
    s_go = (old == NC - 1) ? 1 : 0;
  }
  __syncthreads();
  if (!s_go) return;
  if (tid == 0) __threadfence();   // acquire
  __syncthreads();
  {
    int w = tid >> 6, d = tid & 63;
    for (int t = w; t < Uc; t += 4) {
      int mlbase = bh * NC * Uc + t;       // pM/pL index: + c*Uc
      float m = -INFINITY;
      #pragma unroll 4
      for (int c = 0; c < NC; ++c) m = fmaxf(m, pM[mlbase + c * Uc]);
      float den = 0.f, num = 0.f;
      #pragma unroll 4
      for (int c = 0; c < NC; ++c) {
        float mc = pM[mlbase + c * Uc];
        float wgt = (mc == -INFINITY) ? 0.f : __expf(mc - m);
        den += wgt * pL[mlbase + c * Uc];
        num += wgt * pO[(mlbase + c * Uc) * 64 + d];
      }
      out[((b * Uc + t) * Hc + h) * 64 + d] = num / den;
    }
  }
}

extern "C" void kernel_launch(void* const* d_in, const int* in_sizes, int n_in,
                              void* d_out, int out_size, void* d_ws, size_t ws_size,
                              hipStream_t stream) {
  const float* Q = (const float*)d_in[0];
  const float* K = (const float*)d_in[1];
  const float* V = (const float*)d_in[2];
  const int* amask = (const int*)d_in[3];
  float* out = (float*)d_out;
  char* ws = (char*)d_ws;
  float* M    = (float*)(ws + 0x000000);   // 65536 floats (256 KB)
  int*   topk = (int*)(ws + 0x040000);     // 720 ints
  float* qg   = (float*)(ws + 0x041000);   // 16*45*64 floats (184,320 B)
  int*   cntA = (int*)(ws + 0x06E000);     // 16 ints (scoreM->topk completion)
  int*   cntB = cntA + 16;                 // 16 ints (attn->merge completion)
  float* pM   = (float*)(ws + 0x070000);
  // ws_size is constant across calls -> branch is deterministic (graph-safe).
  size_t need64 = 0x70000UL + 64UL * 190080UL;   // pM+pL+pO for NC=64 (~12.6 MB)
  size_t need32 = 0x70000UL + 32UL * 190080UL;
  int NC = ws_size >= need64 ? 64 : (ws_size >= need32 ? 32 : 16);
  float* pL = pM + 16 * NC * Uc;
  float* pO = pL + 16 * NC * Uc;

  hipMemsetAsync(ws + 0x06E000, 0, 128, stream);   // zero completion counters
  k_scoreM_topk<<<4096, 256, 0, stream>>>(Q, K, M, cntA, topk, qg);
  if (NC == 64) {
    k_attn_merge<64><<<dim3(64, BHc), 256, 0, stream>>>(qg, K, V, amask, pO, pM, pL, cntB, out);
  } else if (NC == 32) {
    k_attn_merge<32><<<dim3(32, BHc), 256, 0, stream>>>(qg, K, V, amask, pO, pM, pL, cntB, out);
  } else {
    k_attn_merge<16><<<dim3(16, BHc), 256, 0, stream>>>(qg, K, V, amask, pO, pM, pL, cntB, out);
  }
}

// Round 7
// 165.437 us; speedup vs baseline: 2.9908x; 2.9908x over previous
//
#include <hip/hip_runtime.h>
#include <math.h>

// ProbSparse attention (Informer). B=2 L=4096 H=8 D=64, U_part=u=45.
// R14: R12 structure restored (4 kernels; fusion rejected -- R13 showed
// per-block device fences cost 2.3x FETCH on scoreM and the last-block
// merge straggler is a 280us serial-latency chain). Change vs R12: k_topk
// only. (a) 4-replica LDS histogram (normal-distributed M collapses into
// ~3 exponent buckets -> pass-0 atomics serialized ~1400-way; replicas cut
// it 4x). (b) suffix-scan via single-wave DPP scan (2 syncs/pass vs ~18;
// 64 -> 8 syncthreads overall). Predict: scoreM unchanged (43us/18MB/57%);
// total 157-162 if topk was contention-bound, ~166 neutral if not (then
// the ~80us residual is launch gaps / in-region fill -> next target).
#define JAX_PARTITIONABLE 1

constexpr int Bc = 2, Lc = 4096, Hc = 8, Dc = 64;
constexpr int BHc = Bc * Hc;     // 16
constexpr int Uc = 45;           // top-k queries
constexpr int NSc = 45;          // samples per query

typedef float vfloat4 __attribute__((ext_vector_type(4)));

struct TF2 { unsigned a, b; };

__host__ __device__ constexpr unsigned rotl32(unsigned v, int n) {
  return (v << n) | (v >> (32 - n));
}

// Threefry-2x32, 20 rounds (JAX reference schedule).
__host__ __device__ constexpr TF2 tf2(unsigned k0, unsigned k1, unsigned x0, unsigned x1) {
  unsigned ks2 = k0 ^ k1 ^ 0x1BD11BDAu;
  x0 += k0; x1 += k1;
  x0 += x1; x1 = rotl32(x1, 13); x1 ^= x0;
  x0 += x1; x1 = rotl32(x1, 15); x1 ^= x0;
  x0 += x1; x1 = rotl32(x1, 26); x1 ^= x0;
  x0 += x1; x1 = rotl32(x1, 6);  x1 ^= x0;
  x0 += k1; x1 += ks2 + 1u;
  x0 += x1; x1 = rotl32(x1, 17); x1 ^= x0;
  x0 += x1; x1 = rotl32(x1, 29); x1 ^= x0;
  x0 += x1; x1 = rotl32(x1, 16); x1 ^= x0;
  x0 += x1; x1 = rotl32(x1, 24); x1 ^= x0;
  x0 += ks2; x1 += k0 + 2u;
  x0 += x1; x1 = rotl32(x1, 13); x1 ^= x0;
  x0 += x1; x1 = rotl32(x1, 15); x1 ^= x0;
  x0 += x1; x1 = rotl32(x1, 26); x1 ^= x0;
  x0 += x1; x1 = rotl32(x1, 6);  x1 ^= x0;
  x0 += k0; x1 += k1 + 3u;
  x0 += x1; x1 = rotl32(x1, 17); x1 ^= x0;
  x0 += x1; x1 = rotl32(x1, 29); x1 ^= x0;
  x0 += x1; x1 = rotl32(x1, 16); x1 ^= x0;
  x0 += x1; x1 = rotl32(x1, 24); x1 ^= x0;
  x0 += k1; x1 += ks2 + 4u;
  x0 += x1; x1 = rotl32(x1, 13); x1 ^= x0;
  x0 += x1; x1 = rotl32(x1, 15); x1 ^= x0;
  x0 += x1; x1 = rotl32(x1, 26); x1 ^= x0;
  x0 += x1; x1 = rotl32(x1, 6);  x1 ^= x0;
  x0 += ks2; x1 += k0 + 5u;
  return TF2{x0, x1};
}

// VALU-pipe partial-sum add via DPP (identity old=0 for invalid lanes).
template <int CTRL>
__device__ __forceinline__ float dpp_add(float x) {
  int t = __builtin_amdgcn_update_dpp(0, __float_as_int(x), CTRL, 0xF, 0xF, false);
  return x + __int_as_float(t);
}
template <int CTRL>
__device__ __forceinline__ int dpp_addi(int x) {
  int t = __builtin_amdgcn_update_dpp(0, x, CTRL, 0xF, 0xF, false);
  return x + t;
}
// DPP-shifted value with own value as identity for invalid lanes (for max).
template <int CTRL>
__device__ __forceinline__ float dpp_idf(float x) {
  int t = __builtin_amdgcn_update_dpp(__float_as_int(x), __float_as_int(x), CTRL, 0xF, 0xF, false);
  return __int_as_float(t);
}
// Full-wave (64-lane) max/sum: result valid at lane 63, broadcast via readlane.
__device__ __forceinline__ float wave_max_bcast(float x) {
  x = fmaxf(x, dpp_idf<0x111>(x));   // row_shr:1
  x = fmaxf(x, dpp_idf<0x112>(x));   // row_shr:2
  x = fmaxf(x, dpp_idf<0x114>(x));   // row_shr:4
  x = fmaxf(x, dpp_idf<0x118>(x));   // row_shr:8  -> lane15 of each row = row max
  x = fmaxf(x, dpp_idf<0x142>(x));   // row_bcast:15
  x = fmaxf(x, dpp_idf<0x143>(x));   // row_bcast:31 -> lane63 = wave max
  return __int_as_float(__builtin_amdgcn_readlane(__float_as_int(x), 63));
}
__device__ __forceinline__ float wave_sum_bcast(float x) {
  x = dpp_add<0x111>(x);
  x = dpp_add<0x112>(x);
  x = dpp_add<0x114>(x);
  x = dpp_add<0x118>(x);
  x = dpp_add<0x142>(x);
  x = dpp_add<0x143>(x);
  return __int_as_float(__builtin_amdgcn_readlane(__float_as_int(x), 63));
}

// fmaf chain for a float4 dot accumulated into a: 4 VALU insts.
__device__ __forceinline__ float dot4_acc(float4 q, float4 k, float a) {
  a = fmaf(q.x, k.x, a);
  a = fmaf(q.y, k.y, a);
  a = fmaf(q.z, k.z, a);
  a = fmaf(q.w, k.w, a);
  return a;
}

// M[bh][q] = max_s dot(Q[q],K[idx[q][s]]) - sum_s(...)/4096.
// bh = blockIdx&15: with round-robin block->XCD dispatch, each XCD sees 2 bh
// -> 2 MB K slices stay L2-resident. At the L2 random-line-rate roofline
// (1.47M 64-B lines/XCD @ ~16 lines/cy ~= 38 us). Threefry stays in-kernel:
// hoisting it (R9-R11) always lost more to L2 pollution than it saved.
__global__ __launch_bounds__(256) void k_scoreM(const float* __restrict__ Q, const float* __restrict__ K,
                                                float* __restrict__ M) {
  __shared__ int sidx[720];
  int tid = threadIdx.x;
  int bx = blockIdx.x;
  int bh = bx & 15;
  int qblk = bx >> 4;              // 0..255
  int b = bh >> 3, h = bh & 7;
  int lane16 = tid & 15, qloc = tid >> 4;
  int q = qblk * 16 + qloc;
  constexpr TF2 kb = tf2(0u, 1u, 0u, 1u);
  for (int e = tid; e < 720; e += 256) {
    TF2 r = tf2(kb.a, kb.b, 0u, (unsigned)(qblk * 720 + e));
    sidx[e] = (int)((r.a ^ r.b) & 4095u);
  }
  __syncthreads();
  const vfloat4* Q4 = (const vfloat4*)Q;
  const vfloat4* K4 = (const vfloat4*)K;
  vfloat4 qr = Q4[((b * Lc + q) * Hc + h) * 16 + lane16];
  int kbase = (b * Lc * Hc + h) * 16 + lane16;
  const int* ip = sidx + qloc * NSc;
  float mx = -INFINITY, sm = 0.f;
  #pragma unroll
  for (int s0 = 0; s0 < NSc; s0 += 5) {      // 5-deep load batch: L2 loads in flight
    int kk[5];
    #pragma unroll
    for (int i = 0; i < 5; ++i) kk[i] = ip[s0 + i];
    vfloat4 kv[5];
    #pragma unroll
    for (int i = 0; i < 5; ++i) kv[i] = __builtin_nontemporal_load(&K4[kbase + kk[i] * (Hc * 16)]);
    #pragma unroll
    for (int i = 0; i < 5; ++i) {
      float p = fmaf(qr[0], kv[i][0], fmaf(qr[1], kv[i][1], fmaf(qr[2], kv[i][2], qr[3] * kv[i][3])));
      p = dpp_add<0x111>(p);                 // row_shr cascade -> lane15 = full dot
      p = dpp_add<0x112>(p);
      p = dpp_add<0x114>(p);
      p = dpp_add<0x118>(p);
      mx = fmaxf(mx, p);                     // valid at lane15; junk elsewhere (never read)
      sm += p;
    }
  }
  if (lane16 == 15) M[bh * Lc + q] = mx - sm * (1.0f / Lc);
}

// Radix-select top-45 of 4096 per bh (exact lax.top_k: value desc, index asc
// on ties). Then pre-gather the 45 selected Q rows into qg[bh][45][64].
// R14: 4-replica histogram (pass-0 atomics were ~1400-way same-address) and
// single-wave DPP suffix-scan (2 syncs/pass vs 18).
__global__ __launch_bounds__(256) void k_topk(const float* __restrict__ M, const float* __restrict__ Q,
                                              int* __restrict__ topk, float* __restrict__ qg) {
  __shared__ unsigned su[Lc];      // 16 KB mapped keys
  __shared__ int hist[4][256];     // replicated: wave w -> hist[w]
  __shared__ int sfx[257];
  __shared__ unsigned s_prefix;
  __shared__ int s_r;
  __shared__ int n_gt, n_eq;
  __shared__ unsigned cu[64];
  __shared__ int cidx[64];
  __shared__ int eqi[64];
  __shared__ int srank[Uc];
  int bh = blockIdx.x, tid = threadIdx.x;
  int b = bh >> 3, h = bh & 7;
  int w = tid >> 6;
  const float* m = M + bh * Lc;
  for (int e = tid; e < Lc; e += 256) {
    unsigned bb = __float_as_uint(m[e]);
    su[e] = (bb & 0x80000000u) ? ~bb : (bb | 0x80000000u);
  }
  if (tid == 0) { s_r = Uc; s_prefix = 0u; n_gt = 0; n_eq = 0; sfx[256] = 0; }
  __syncthreads();
  #pragma unroll
  for (int p = 0; p < 4; ++p) {
    int shift = 24 - 8 * p;
    hist[0][tid] = 0; hist[1][tid] = 0; hist[2][tid] = 0; hist[3][tid] = 0;
    __syncthreads();
    unsigned pref = s_prefix;
    unsigned hmask = (p == 0) ? 0u : (0xFFFFFFFFu << (shift + 8));
    for (int e = tid; e < Lc; e += 256) {
      unsigned u = su[e];
      if ((u & hmask) == pref) atomicAdd(&hist[w][(u >> shift) & 255u], 1);
    }
    __syncthreads();
    if (tid < 64) {
      // Suffix sums via one-wave scan: lane l covers rev-indices 4l..4l+3,
      // i.e. buckets i0=255-4l down to i0-3. Local inclusive + DPP wave scan.
      int i0 = 255 - 4 * tid;
      int h0 = hist[0][i0]     + hist[1][i0]     + hist[2][i0]     + hist[3][i0];
      int h1 = hist[0][i0 - 1] + hist[1][i0 - 1] + hist[2][i0 - 1] + hist[3][i0 - 1];
      int h2 = hist[0][i0 - 2] + hist[1][i0 - 2] + hist[2][i0 - 2] + hist[3][i0 - 2];
      int h3 = hist[0][i0 - 3] + hist[1][i0 - 3] + hist[2][i0 - 3] + hist[3][i0 - 3];
      int s0i = h0, s1i = s0i + h1, s2i = s1i + h2, s3i = s2i + h3;
      int tot = s3i;
      int x = tot;
      x = dpp_addi<0x111>(x);          // row_shr:1
      x = dpp_addi<0x112>(x);          // row_shr:2
      x = dpp_addi<0x114>(x);          // row_shr:4
      x = dpp_addi<0x118>(x);          // row_shr:8 -> per-16-row inclusive
      int r0 = __builtin_amdgcn_readlane(x, 15);
      int r1 = __builtin_amdgcn_readlane(x, 31);
      int r2 = __builtin_amdgcn_readlane(x, 47);
      if (tid >= 16) x += r0;
      if (tid >= 32) x += r1;
      if (tid >= 48) x += r2;          // 64-lane inclusive scan of tot
      int excl = x - tot;
      sfx[i0]     = excl + s0i;
      sfx[i0 - 1] = excl + s1i;
      sfx[i0 - 2] = excl + s2i;
      sfx[i0 - 3] = excl + s3i;
    }
    __syncthreads();
    int r = s_r;
    __syncthreads();                            // all read s_r before update
    int above = sfx[tid + 1];                   // sfx[256]==0 sentinel
    if (sfx[tid] >= r && above < r) {           // unique digit
      s_r = r - above;
      s_prefix = pref | ((unsigned)tid << shift);
    }
    __syncthreads();
  }
  unsigned T = s_prefix;                        // exact 45th-largest key
  int rf = s_r;                                 // #equals to take (>=1)
  for (int e = tid; e < Lc; e += 256) {
    unsigned u = su[e];
    if (u > T) {
      int p = atomicAdd(&n_gt, 1);              // <= 44
      cu[p] = u; cidx[p] = e;
    } else if (u == T) {
      int p = atomicAdd(&n_eq, 1);
      if (p < 64) eqi[p] = e;                   // >64-way ties: impossible for random-normal M
    }
  }
  __syncthreads();
  int ne = n_eq < 64 ? n_eq : 64;
  if (tid < ne) {
    int myi = eqi[tid];
    int rank = 0;
    for (int j = 0; j < ne; ++j) rank += (eqi[j] < myi);
    if (rank < rf) {
      int p = atomicAdd(&n_gt, 1);              // completes to exactly 45
      cu[p] = T; cidx[p] = myi;
    }
  }
  __syncthreads();
  if (tid < Uc) {
    unsigned mu = cu[tid]; int mi = cidx[tid];
    int rank = 0;
    for (int j = 0; j < Uc; ++j) {
      unsigned ju = cu[j]; int ji = cidx[j];
      rank += (ju > mu) || (ju == mu && ji < mi);
    }
    topk[bh * Uc + rank] = mi;
    srank[rank] = mi;
  }
  __syncthreads();
  const float4* Q4 = (const float4*)Q;
  float4* qg4 = (float4*)qg;
  for (int e = tid; e < Uc * 16; e += 256) {    // coalesced pre-gather of selected Q rows
    int t = e >> 4, dq = e & 15;
    qg4[bh * Uc * 16 + e] = Q4[((b * Lc + srank[t]) * Hc + h) * 16 + dq];
  }
}

// Flash-decoding partials: one block per (bh, CH-key chunk), CH = 4096/NC.
// NOTE: phase 2 assumes CH == 64 (one wave per score row); the NC=64 path is
// always taken in practice (ws_size >> 13 MB).
template<int NC>
__global__ __launch_bounds__(256) void k_attn(const float* __restrict__ qg, const float* __restrict__ K,
                                              const float* __restrict__ V, const int* __restrict__ amask,
                                              float* __restrict__ pO, float* __restrict__ pM,
                                              float* __restrict__ pL) {
  constexpr int CH = Lc / NC;
  constexpr int TG = 256 / CH;
  constexpr int SCW = CH + 4;      // row stride 68 floats = 272 B (16-B aligned rows)
  int chunk = blockIdx.x, bh = blockIdx.y;
  int b = bh >> 3, h = bh & 7;
  int tid = threadIdx.x;
  __shared__ __align__(16) float qs[Uc * 64];
  __shared__ __align__(16) float sc[48][SCW];
  {
    const float4* qg4 = (const float4*)qg;
    float4* qs4w = (float4*)qs;
    for (int e = tid; e < Uc * 16; e += 256) qs4w[e] = qg4[bh * Uc * 16 + e];
  }
  for (int e = tid; e < 3 * SCW; e += 256) sc[45 + e / SCW][e % SCW] = 0.f;
  __syncthreads();
  {
    int k = tid % CH, tg = tid / CH;
    int key = chunk * CH + k;
    const float4* K4 = (const float4*)K;
    int kb = ((b * Lc + key) * Hc + h) * 16;
    float4 kr[16];
    #pragma unroll
    for (int j = 0; j < 16; ++j) kr[j] = K4[kb + j];
    int mk = amask[b * Lc + key];
    const float4* qs4 = (const float4*)qs;
    for (int t = tg; t < Uc; t += TG) {
      float a0 = 0.f, a1 = 0.f, a2 = 0.f, a3 = 0.f;   // 4 independent fmaf chains
      #pragma unroll
      for (int j = 0; j < 16; j += 4) {
        a0 = dot4_acc(qs4[t * 16 + j],     kr[j],     a0);
        a1 = dot4_acc(qs4[t * 16 + j + 1], kr[j + 1], a1);
        a2 = dot4_acc(qs4[t * 16 + j + 2], kr[j + 2], a2);
        a3 = dot4_acc(qs4[t * 16 + j + 3], kr[j + 3], a3);
      }
      float acc = (a0 + a1) + (a2 + a3);
      sc[t][k] = mk ? acc * 0.125f : -INFINITY;
    }
  }
  __syncthreads();
  {
    // CH=64: one wave per score row; DPP reductions (VALU pipe).
    int w = tid >> 6, lane = tid & 63;
    for (int t = w; t < Uc; t += 4) {
      float x = sc[t][lane];
      float ml = wave_max_bcast(x);
      float p = (ml != -INFINITY) ? __expf(x - ml) : 0.f;   // fully-masked chunk guard
      sc[t][lane] = p;
      float ls = wave_sum_bcast(p);
      if (lane == 0) {
        pM[(bh * NC + chunk) * Uc + t] = ml;
        pL[(bh * NC + chunk) * Uc + t] = ls;
      }
    }
  }
  __syncthreads();
  {
    int ty = tid >> 4, tx = tid & 15;
    float4 o0 = {0.f, 0.f, 0.f, 0.f};
    float4 o1 = {0.f, 0.f, 0.f, 0.f};
    float4 o2 = {0.f, 0.f, 0.f, 0.f};
    const float4* V4 = (const float4*)V;
    const float4* s0 = (const float4*)&sc[ty][0];        // rows 16-B aligned (SCW=68)
    const float4* s1 = (const float4*)&sc[ty + 16][0];
    const float4* s2 = (const float4*)&sc[ty + 32][0];
    int vbase = (b * Lc + chunk * CH) * (Hc * 16) + h * 16 + tx;
    #pragma unroll 2
    for (int kq = 0; kq < CH / 4; ++kq) {
      float4 p0 = s0[kq], p1 = s1[kq], p2 = s2[kq];      // 4 keys per ds_read_b128
      float4 va = V4[vbase + (4 * kq + 0) * (Hc * 16)];
      float4 vb = V4[vbase + (4 * kq + 1) * (Hc * 16)];
      float4 vc = V4[vbase + (4 * kq + 2) * (Hc * 16)];
      float4 vd = V4[vbase + (4 * kq + 3) * (Hc * 16)];
      o0.x = fmaf(p0.x, va.x, o0.x); o0.y = fmaf(p0.x, va.y, o0.y); o0.z = fmaf(p0.x, va.z, o0.z); o0.w = fmaf(p0.x, va.w, o0.w);
      o1.x = fmaf(p1.x, va.x, o1.x); o1.y = fmaf(p1.x, va.y, o1.y); o1.z = fmaf(p1.x, va.z, o1.z); o1.w = fmaf(p1.x, va.w, o1.w);
      o2.x = fmaf(p2.x, va.x, o2.x); o2.y = fmaf(p2.x, va.y, o2.y); o2.z = fmaf(p2.x, va.z, o2.z); o2.w = fmaf(p2.x, va.w, o2.w);
      o0.x = fmaf(p0.y, vb.x, o0.x); o0.y = fmaf(p0.y, vb.y, o0.y); o0.z = fmaf(p0.y, vb.z, o0.z); o0.w = fmaf(p0.y, vb.w, o0.w);
      o1.x = fmaf(p1.y, vb.x, o1.x); o1.y = fmaf(p1.y, vb.y, o1.y); o1.z = fmaf(p1.y, vb.z, o1.z); o1.w = fmaf(p1.y, vb.w, o1.w);
      o2.x = fmaf(p2.y, vb.x, o2.x); o2.y = fmaf(p2.y, vb.y, o2.y); o2.z = fmaf(p2.y, vb.z, o2.z); o2.w = fmaf(p2.y, vb.w, o2.w);
      o0.x = fmaf(p0.z, vc.x, o0.x); o0.y = fmaf(p0.z, vc.y, o0.y); o0.z = fmaf(p0.z, vc.z, o0.z); o0.w = fmaf(p0.z, vc.w, o0.w);
      o1.x = fmaf(p1.z, vc.x, o1.x); o1.y = fmaf(p1.z, vc.y, o1.y); o1.z = fmaf(p1.z, vc.z, o1.z); o1.w = fmaf(p1.z, vc.w, o1.w);
      o2.x = fmaf(p2.z, vc.x, o2.x); o2.y = fmaf(p2.z, vc.y, o2.y); o2.z = fmaf(p2.z, vc.z, o2.z); o2.w = fmaf(p2.z, vc.w, o2.w);
      o0.x = fmaf(p0.w, vd.x, o0.x); o0.y = fmaf(p0.w, vd.y, o0.y); o0.z = fmaf(p0.w, vd.z, o0.z); o0.w = fmaf(p0.w, vd.w, o0.w);
      o1.x = fmaf(p1.w, vd.x, o1.x); o1.y = fmaf(p1.w, vd.y, o1.y); o1.z = fmaf(p1.w, vd.z, o1.z); o1.w = fmaf(p1.w, vd.w, o1.w);
      o2.x = fmaf(p2.w, vd.x, o2.x); o2.y = fmaf(p2.w, vd.y, o2.y); o2.z = fmaf(p2.w, vd.z, o2.z); o2.w = fmaf(p2.w, vd.w, o2.w);
    }
    float4* pO4 = (float4*)pO;
    int obase = ((bh * NC + chunk) * Uc) * 16 + tx;
    pO4[obase + ty * 16] = o0;
    pO4[obase + (ty + 16) * 16] = o1;
    if (ty < 13) pO4[obase + (ty + 32) * 16] = o2;
  }
}

// Exact merge of chunk partials; out[b][t][h][d].
// One block per (bh,t) = 720 blocks. Thread (cg,d): cg=tid>>6 covers NC/4
// chunks, d=tid&63 one output dim. 2-sync LDS combine.
template<int NC>
__global__ __launch_bounds__(256) void k_merge(const float* __restrict__ pO, const float* __restrict__ pM,
                                               const float* __restrict__ pL, float* __restrict__ out) {
  constexpr int CPT = NC / 4;          // chunks per thread-group
  __shared__ float smax[4];
  __shared__ float sden[4];
  __shared__ float snum[4][64];
  int bid = blockIdx.x;                // 720 = 45*16, bid = t*16 + bh
  int bh = bid & 15, t = bid >> 4;
  int b = bh >> 3, h = bh & 7;
  int tid = threadIdx.x;
  int d = tid & 63, cg = tid >> 6;
  int mlbase = bh * NC * Uc + t;       // pM/pL index: + c*Uc
  float lm = -INFINITY;
  #pragma unroll 4
  for (int c = cg * CPT; c < (cg + 1) * CPT; ++c)
    lm = fmaxf(lm, pM[mlbase + c * Uc]);
  if (d == 0) smax[cg] = lm;
  __syncthreads();
  float m = fmaxf(fmaxf(smax[0], smax[1]), fmaxf(smax[2], smax[3]));
  float den = 0.f, num = 0.f;
  #pragma unroll 4
  for (int c = cg * CPT; c < (cg + 1) * CPT; ++c) {
    float mc = pM[mlbase + c * Uc];
    float wgt = (mc == -INFINITY) ? 0.f : __expf(mc - m);
    den += wgt * pL[mlbase + c * Uc];
    num += wgt * pO[(mlbase + c * Uc) * 64 + d];
  }
  if (d == 0) sden[cg] = den;
  snum[cg][d] = num;
  __syncthreads();
  if (cg == 0) {
    float dn = sden[0] + sden[1] + sden[2] + sden[3];
    float nm = snum[0][d] + snum[1][d] + snum[2][d] + snum[3][d];
    out[((b * Uc + t) * Hc + h) * 64 + d] = nm / dn;
  }
}

extern "C" void kernel_launch(void* const* d_in, const int* in_sizes, int n_in,
                              void* d_out, int out_size, void* d_ws, size_t ws_size,
                              hipStream_t stream) {
  const float* Q = (const float*)d_in[0];
  const float* K = (const float*)d_in[1];
  const float* V = (const float*)d_in[2];
  const int* amask = (const int*)d_in[3];
  float* out = (float*)d_out;
  char* ws = (char*)d_ws;
  float* M    = (float*)(ws + 0x000000);   // 65536 floats (256 KB)
  int*   topk = (int*)(ws + 0x040000);     // 720 ints
  float* qg   = (float*)(ws + 0x041000);   // 16*45*64 floats (184,320 B)
  float* pM   = (float*)(ws + 0x070000);
  // ws_size is constant across calls -> branch is deterministic (graph-safe).
  size_t need64 = 0x70000UL + 64UL * 190080UL;   // pM+pL+pO for NC=64 (~12.6 MB)
  size_t need32 = 0x70000UL + 32UL * 190080UL;
  int NC = ws_size >= need64 ? 64 : (ws_size >= need32 ? 32 : 16);
  float* pL = pM + 16 * NC * Uc;
  float* pO = pL + 16 * NC * Uc;

  k_scoreM<<<4096, 256, 0, stream>>>(Q, K, M);
  k_topk<<<BHc, 256, 0, stream>>>(M, Q, topk, qg);
  if (NC == 64) {
    k_attn<64><<<dim3(64, BHc), 256, 0, stream>>>(qg, K, V, amask, pO, pM, pL);
    k_merge<64><<<BHc * Uc, 256, 0, stream>>>(pO, pM, pL, out);
  } else if (NC == 32) {
    k_attn<32><<<dim3(32, BHc), 256, 0, stream>>>(qg, K, V, amask, pO, pM, pL);
    k_merge<32><<<BHc * Uc, 256, 0, stream>>>(pO, pM, pL, out);
  } else {
    k_attn<16><<<dim3(16, BHc), 256, 0, stream>>>(qg, K, V, amask, pO, pM, pL);
    k_merge<16><<<BHc * Uc, 256, 0, stream>>>(pO, pM, pL, out);
  }
}

// Round 8
// 164.181 us; speedup vs baseline: 3.0137x; 1.0076x over previous
//
#include <hip/hip_runtime.h>
#include <math.h>

// ProbSparse attention (Informer). B=2 L=4096 H=8 D=64, U_part=u=45.
// R15: single change vs R14 -- __launch_bounds__(256, 4) on k_attn.
// Evidence: R13's fused attn showed VGPR_Count=52, but phase 1 declares
// float4 kr[16] = 64 VGPRs of K-row. 52 < 64 -> kr is NOT register-resident;
// the compiler re-loads the K row from L2 inside the t-loop (~11.5x/thread,
// ~688 MB extra L2 traffic ~= 20us at the 34.5 TB/s L2 ceiling + 690K VMEM
// issues). Bare __launch_bounds__(256) let the allocator trade registers
// for occupancy; (256,4) = 4 blocks/CU min -> VGPR cap 128, kr fits, LDS
// (24.6KB) still allows 6 blocks/CU. Predict: attn -15..25us -> total
// 142-152 if theory right; neutral ~165 means attn small -> residual is
// harness fill / gaps (practical floor). R14's topk kept (neutral, cheaper
// syncs); scoreM/merge byte-identical.
#define JAX_PARTITIONABLE 1

constexpr int Bc = 2, Lc = 4096, Hc = 8, Dc = 64;
constexpr int BHc = Bc * Hc;     // 16
constexpr int Uc = 45;           // top-k queries
constexpr int NSc = 45;          // samples per query

typedef float vfloat4 __attribute__((ext_vector_type(4)));

struct TF2 { unsigned a, b; };

__host__ __device__ constexpr unsigned rotl32(unsigned v, int n) {
  return (v << n) | (v >> (32 - n));
}

// Threefry-2x32, 20 rounds (JAX reference schedule).
__host__ __device__ constexpr TF2 tf2(unsigned k0, unsigned k1, unsigned x0, unsigned x1) {
  unsigned ks2 = k0 ^ k1 ^ 0x1BD11BDAu;
  x0 += k0; x1 += k1;
  x0 += x1; x1 = rotl32(x1, 13); x1 ^= x0;
  x0 += x1; x1 = rotl32(x1, 15); x1 ^= x0;
  x0 += x1; x1 = rotl32(x1, 26); x1 ^= x0;
  x0 += x1; x1 = rotl32(x1, 6);  x1 ^= x0;
  x0 += k1; x1 += ks2 + 1u;
  x0 += x1; x1 = rotl32(x1, 17); x1 ^= x0;
  x0 += x1; x1 = rotl32(x1, 29); x1 ^= x0;
  x0 += x1; x1 = rotl32(x1, 16); x1 ^= x0;
  x0 += x1; x1 = rotl32(x1, 24); x1 ^= x0;
  x0 += ks2; x1 += k0 + 2u;
  x0 += x1; x1 = rotl32(x1, 13); x1 ^= x0;
  x0 += x1; x1 = rotl32(x1, 15); x1 ^= x0;
  x0 += x1; x1 = rotl32(x1, 26); x1 ^= x0;
  x0 += x1; x1 = rotl32(x1, 6);  x1 ^= x0;
  x0 += k0; x1 += k1 + 3u;
  x0 += x1; x1 = rotl32(x1, 17); x1 ^= x0;
  x0 += x1; x1 = rotl32(x1, 29); x1 ^= x0;
  x0 += x1; x1 = rotl32(x1, 16); x1 ^= x0;
  x0 += x1; x1 = rotl32(x1, 24); x1 ^= x0;
  x0 += k1; x1 += ks2 + 4u;
  x0 += x1; x1 = rotl32(x1, 13); x1 ^= x0;
  x0 += x1; x1 = rotl32(x1, 15); x1 ^= x0;
  x0 += x1; x1 = rotl32(x1, 26); x1 ^= x0;
  x0 += x1; x1 = rotl32(x1, 6);  x1 ^= x0;
  x0 += ks2; x1 += k0 + 5u;
  return TF2{x0, x1};
}

// VALU-pipe partial-sum add via DPP (identity old=0 for invalid lanes).
template <int CTRL>
__device__ __forceinline__ float dpp_add(float x) {
  int t = __builtin_amdgcn_update_dpp(0, __float_as_int(x), CTRL, 0xF, 0xF, false);
  return x + __int_as_float(t);
}
template <int CTRL>
__device__ __forceinline__ int dpp_addi(int x) {
  int t = __builtin_amdgcn_update_dpp(0, x, CTRL, 0xF, 0xF, false);
  return x + t;
}
// DPP-shifted value with own value as identity for invalid lanes (for max).
template <int CTRL>
__device__ __forceinline__ float dpp_idf(float x) {
  int t = __builtin_amdgcn_update_dpp(__float_as_int(x), __float_as_int(x), CTRL, 0xF, 0xF, false);
  return __int_as_float(t);
}
// Full-wave (64-lane) max/sum: result valid at lane 63, broadcast via readlane.
__device__ __forceinline__ float wave_max_bcast(float x) {
  x = fmaxf(x, dpp_idf<0x111>(x));   // row_shr:1
  x = fmaxf(x, dpp_idf<0x112>(x));   // row_shr:2
  x = fmaxf(x, dpp_idf<0x114>(x));   // row_shr:4
  x = fmaxf(x, dpp_idf<0x118>(x));   // row_shr:8  -> lane15 of each row = row max
  x = fmaxf(x, dpp_idf<0x142>(x));   // row_bcast:15
  x = fmaxf(x, dpp_idf<0x143>(x));   // row_bcast:31 -> lane63 = wave max
  return __int_as_float(__builtin_amdgcn_readlane(__float_as_int(x), 63));
}
__device__ __forceinline__ float wave_sum_bcast(float x) {
  x = dpp_add<0x111>(x);
  x = dpp_add<0x112>(x);
  x = dpp_add<0x114>(x);
  x = dpp_add<0x118>(x);
  x = dpp_add<0x142>(x);
  x = dpp_add<0x143>(x);
  return __int_as_float(__builtin_amdgcn_readlane(__float_as_int(x), 63));
}

// fmaf chain for a float4 dot accumulated into a: 4 VALU insts.
__device__ __forceinline__ float dot4_acc(float4 q, float4 k, float a) {
  a = fmaf(q.x, k.x, a);
  a = fmaf(q.y, k.y, a);
  a = fmaf(q.z, k.z, a);
  a = fmaf(q.w, k.w, a);
  return a;
}

// M[bh][q] = max_s dot(Q[q],K[idx[q][s]]) - sum_s(...)/4096.
// bh = blockIdx&15: with round-robin block->XCD dispatch, each XCD sees 2 bh
// -> 2 MB K slices stay L2-resident. At the L2 random-line-rate roofline
// (1.47M 64-B lines/XCD @ ~16 lines/cy ~= 38 us). Threefry stays in-kernel:
// hoisting it (R9-R11) always lost more to L2 pollution than it saved.
__global__ __launch_bounds__(256) void k_scoreM(const float* __restrict__ Q, const float* __restrict__ K,
                                                float* __restrict__ M) {
  __shared__ int sidx[720];
  int tid = threadIdx.x;
  int bx = blockIdx.x;
  int bh = bx & 15;
  int qblk = bx >> 4;              // 0..255
  int b = bh >> 3, h = bh & 7;
  int lane16 = tid & 15, qloc = tid >> 4;
  int q = qblk * 16 + qloc;
  constexpr TF2 kb = tf2(0u, 1u, 0u, 1u);
  for (int e = tid; e < 720; e += 256) {
    TF2 r = tf2(kb.a, kb.b, 0u, (unsigned)(qblk * 720 + e));
    sidx[e] = (int)((r.a ^ r.b) & 4095u);
  }
  __syncthreads();
  const vfloat4* Q4 = (const vfloat4*)Q;
  const vfloat4* K4 = (const vfloat4*)K;
  vfloat4 qr = Q4[((b * Lc + q) * Hc + h) * 16 + lane16];
  int kbase = (b * Lc * Hc + h) * 16 + lane16;
  const int* ip = sidx + qloc * NSc;
  float mx = -INFINITY, sm = 0.f;
  #pragma unroll
  for (int s0 = 0; s0 < NSc; s0 += 5) {      // 5-deep load batch: L2 loads in flight
    int kk[5];
    #pragma unroll
    for (int i = 0; i < 5; ++i) kk[i] = ip[s0 + i];
    vfloat4 kv[5];
    #pragma unroll
    for (int i = 0; i < 5; ++i) kv[i] = __builtin_nontemporal_load(&K4[kbase + kk[i] * (Hc * 16)]);
    #pragma unroll
    for (int i = 0; i < 5; ++i) {
      float p = fmaf(qr[0], kv[i][0], fmaf(qr[1], kv[i][1], fmaf(qr[2], kv[i][2], qr[3] * kv[i][3])));
      p = dpp_add<0x111>(p);                 // row_shr cascade -> lane15 = full dot
      p = dpp_add<0x112>(p);
      p = dpp_add<0x114>(p);
      p = dpp_add<0x118>(p);
      mx = fmaxf(mx, p);                     // valid at lane15; junk elsewhere (never read)
      sm += p;
    }
  }
  if (lane16 == 15) M[bh * Lc + q] = mx - sm * (1.0f / Lc);
}

// Radix-select top-45 of 4096 per bh (exact lax.top_k: value desc, index asc
// on ties). Then pre-gather the 45 selected Q rows into qg[bh][45][64].
// R14: 4-replica histogram + single-wave DPP suffix-scan (kept; neutral but
// not harmful).
__global__ __launch_bounds__(256) void k_topk(const float* __restrict__ M, const float* __restrict__ Q,
                                              int* __restrict__ topk, float* __restrict__ qg) {
  __shared__ unsigned su[Lc];      // 16 KB mapped keys
  __shared__ int hist[4][256];     // replicated: wave w -> hist[w]
  __shared__ int sfx[257];
  __shared__ unsigned s_prefix;
  __shared__ int s_r;
  __shared__ int n_gt, n_eq;
  __shared__ unsigned cu[64];
  __shared__ int cidx[64];
  __shared__ int eqi[64];
  __shared__ int srank[Uc];
  int bh = blockIdx.x, tid = threadIdx.x;
  int b = bh >> 3, h = bh & 7;
  int w = tid >> 6;
  const float* m = M + bh * Lc;
  for (int e = tid; e < Lc; e += 256) {
    unsigned bb = __float_as_uint(m[e]);
    su[e] = (bb & 0x80000000u) ? ~bb : (bb | 0x80000000u);
  }
  if (tid == 0) { s_r = Uc; s_prefix = 0u; n_gt = 0; n_eq = 0; sfx[256] = 0; }
  __syncthreads();
  #pragma unroll
  for (int p = 0; p < 4; ++p) {
    int shift = 24 - 8 * p;
    hist[0][tid] = 0; hist[1][tid] = 0; hist[2][tid] = 0; hist[3][tid] = 0;
    __syncthreads();
    unsigned pref = s_prefix;
    unsigned hmask = (p == 0) ? 0u : (0xFFFFFFFFu << (shift + 8));
    for (int e = tid; e < Lc; e += 256) {
      unsigned u = su[e];
      if ((u & hmask) == pref) atomicAdd(&hist[w][(u >> shift) & 255u], 1);
    }
    __syncthreads();
    if (tid < 64) {
      // Suffix sums via one-wave scan: lane l covers rev-indices 4l..4l+3,
      // i.e. buckets i0=255-4l down to i0-3. Local inclusive + DPP wave scan.
      int i0 = 255 - 4 * tid;
      int h0 = hist[0][i0]     + hist[1][i0]     + hist[2][i0]     + hist[3][i0];
      int h1 = hist[0][i0 - 1] + hist[1][i0 - 1] + hist[2][i0 - 1] + hist[3][i0 - 1];
      int h2 = hist[0][i0 - 2] + hist[1][i0 - 2] + hist[2][i0 - 2] + hist[3][i0 - 2];
      int h3 = hist[0][i0 - 3] + hist[1][i0 - 3] + hist[2][i0 - 3] + hist[3][i0 - 3];
      int s0i = h0, s1i = s0i + h1, s2i = s1i + h2, s3i = s2i + h3;
      int tot = s3i;
      int x = tot;
      x = dpp_addi<0x111>(x);          // row_shr:1
      x = dpp_addi<0x112>(x);          // row_shr:2
      x = dpp_addi<0x114>(x);          // row_shr:4
      x = dpp_addi<0x118>(x);          // row_shr:8 -> per-16-row inclusive
      int r0 = __builtin_amdgcn_readlane(x, 15);
      int r1 = __builtin_amdgcn_readlane(x, 31);
      int r2 = __builtin_amdgcn_readlane(x, 47);
      if (tid >= 16) x += r0;
      if (tid >= 32) x += r1;
      if (tid >= 48) x += r2;          // 64-lane inclusive scan of tot
      int excl = x - tot;
      sfx[i0]     = excl + s0i;
      sfx[i0 - 1] = excl + s1i;
      sfx[i0 - 2] = excl + s2i;
      sfx[i0 - 3] = excl + s3i;
    }
    __syncthreads();
    int r = s_r;
    __syncthreads();                            // all read s_r before update
    int above = sfx[tid + 1];                   // sfx[256]==0 sentinel
    if (sfx[tid] >= r && above < r) {           // unique digit
      s_r = r - above;
      s_prefix = pref | ((unsigned)tid << shift);
    }
    __syncthreads();
  }
  unsigned T = s_prefix;                        // exact 45th-largest key
  int rf = s_r;                                 // #equals to take (>=1)
  for (int e = tid; e < Lc; e += 256) {
    unsigned u = su[e];
    if (u > T) {
      int p = atomicAdd(&n_gt, 1);              // <= 44
      cu[p] = u; cidx[p] = e;
    } else if (u == T) {
      int p = atomicAdd(&n_eq, 1);
      if (p < 64) eqi[p] = e;                   // >64-way ties: impossible for random-normal M
    }
  }
  __syncthreads();
  int ne = n_eq < 64 ? n_eq : 64;
  if (tid < ne) {
    int myi = eqi[tid];
    int rank = 0;
    for (int j = 0; j < ne; ++j) rank += (eqi[j] < myi);
    if (rank < rf) {
      int p = atomicAdd(&n_gt, 1);              // completes to exactly 45
      cu[p] = T; cidx[p] = myi;
    }
  }
  __syncthreads();
  if (tid < Uc) {
    unsigned mu = cu[tid]; int mi = cidx[tid];
    int rank = 0;
    for (int j = 0; j < Uc; ++j) {
      unsigned ju = cu[j]; int ji = cidx[j];
      rank += (ju > mu) || (ju == mu && ji < mi);
    }
    topk[bh * Uc + rank] = mi;
    srank[rank] = mi;
  }
  __syncthreads();
  const float4* Q4 = (const float4*)Q;
  float4* qg4 = (float4*)qg;
  for (int e = tid; e < Uc * 16; e += 256) {    // coalesced pre-gather of selected Q rows
    int t = e >> 4, dq = e & 15;
    qg4[bh * Uc * 16 + e] = Q4[((b * Lc + srank[t]) * Hc + h) * 16 + dq];
  }
}

// Flash-decoding partials: one block per (bh, CH-key chunk), CH = 4096/NC.
// R15: __launch_bounds__(256, 4) -> VGPR cap 128 so kr[16] (64 VGPRs of
// K-row) stays register-resident across the t-loop (was VGPR 52 -> K row
// re-loaded from L2 ~11.5x/thread, ~688 MB extra L2 traffic). LDS 24.6 KB
// still allows 6 blocks/CU, so the 4-block/CU min occupancy is satisfiable.
// NOTE: phase 2 assumes CH == 64; the NC=64 path is always taken (ws_size).
template<int NC>
__global__ __launch_bounds__(256, 4) void k_attn(const float* __restrict__ qg, const float* __restrict__ K,
                                                 const float* __restrict__ V, const int* __restrict__ amask,
                                                 float* __restrict__ pO, float* __restrict__ pM,
                                                 float* __restrict__ pL) {
  constexpr int CH = Lc / NC;
  constexpr int TG = 256 / CH;
  constexpr int SCW = CH + 4;      // row stride 68 floats = 272 B (16-B aligned rows)
  int chunk = blockIdx.x, bh = blockIdx.y;
  int b = bh >> 3, h = bh & 7;
  int tid = threadIdx.x;
  __shared__ __align__(16) float qs[Uc * 64];
  __shared__ __align__(16) float sc[48][SCW];
  {
    const float4* qg4 = (const float4*)qg;
    float4* qs4w = (float4*)qs;
    for (int e = tid; e < Uc * 16; e += 256) qs4w[e] = qg4[bh * Uc * 16 + e];
  }
  for (int e = tid; e < 3 * SCW; e += 256) sc[45 + e / SCW][e % SCW] = 0.f;
  __syncthreads();
  {
    int k = tid % CH, tg = tid / CH;
    int key = chunk * CH + k;
    const float4* K4 = (const float4*)K;
    int kb = ((b * Lc + key) * Hc + h) * 16;
    float4 kr[16];
    #pragma unroll
    for (int j = 0; j < 16; ++j) kr[j] = K4[kb + j];
    int mk = amask[b * Lc + key];
    const float4* qs4 = (const float4*)qs;
    for (int t = tg; t < Uc; t += TG) {
      float a0 = 0.f, a1 = 0.f, a2 = 0.f, a3 = 0.f;   // 4 independent fmaf chains
      #pragma unroll
      for (int j = 0; j < 16; j += 4) {
        a0 = dot4_acc(qs4[t * 16 + j],     kr[j],     a0);
        a1 = dot4_acc(qs4[t * 16 + j + 1], kr[j + 1], a1);
        a2 = dot4_acc(qs4[t * 16 + j + 2], kr[j + 2], a2);
        a3 = dot4_acc(qs4[t * 16 + j + 3], kr[j + 3], a3);
      }
      float acc = (a0 + a1) + (a2 + a3);
      sc[t][k] = mk ? acc * 0.125f : -INFINITY;
    }
  }
  __syncthreads();
  {
    // CH=64: one wave per score row; DPP reductions (VALU pipe).
    int w = tid >> 6, lane = tid & 63;
    for (int t = w; t < Uc; t += 4) {
      float x = sc[t][lane];
      float ml = wave_max_bcast(x);
      float p = (ml != -INFINITY) ? __expf(x - ml) : 0.f;   // fully-masked chunk guard
      sc[t][lane] = p;
      float ls = wave_sum_bcast(p);
      if (lane == 0) {
        pM[(bh * NC + chunk) * Uc + t] = ml;
        pL[(bh * NC + chunk) * Uc + t] = ls;
      }
    }
  }
  __syncthreads();
  {
    int ty = tid >> 4, tx = tid & 15;
    float4 o0 = {0.f, 0.f, 0.f, 0.f};
    float4 o1 = {0.f, 0.f, 0.f, 0.f};
    float4 o2 = {0.f, 0.f, 0.f, 0.f};
    const float4* V4 = (const float4*)V;
    const float4* s0 = (const float4*)&sc[ty][0];        // rows 16-B aligned (SCW=68)
    const float4* s1 = (const float4*)&sc[ty + 16][0];
    const float4* s2 = (const float4*)&sc[ty + 32][0];
    int vbase = (b * Lc + chunk * CH) * (Hc * 16) + h * 16 + tx;
    #pragma unroll 2
    for (int kq = 0; kq < CH / 4; ++kq) {
      float4 p0 = s0[kq], p1 = s1[kq], p2 = s2[kq];      // 4 keys per ds_read_b128
      float4 va = V4[vbase + (4 * kq + 0) * (Hc * 16)];
      float4 vb = V4[vbase + (4 * kq + 1) * (Hc * 16)];
      float4 vc = V4[vbase + (4 * kq + 2) * (Hc * 16)];
      float4 vd = V4[vbase + (4 * kq + 3) * (Hc * 16)];
      o0.x = fmaf(p0.x, va.x, o0.x); o0.y = fmaf(p0.x, va.y, o0.y); o0.z = fmaf(p0.x, va.z, o0.z); o0.w = fmaf(p0.x, va.w, o0.w);
      o1.x = fmaf(p1.x, va.x, o1.x); o1.y = fmaf(p1.x, va.y, o1.y); o1.z = fmaf(p1.x, va.z, o1.z); o1.w = fmaf(p1.x, va.w, o1.w);
      o2.x = fmaf(p2.x, va.x, o2.x); o2.y = fmaf(p2.x, va.y, o2.y); o2.z = fmaf(p2.x, va.z, o2.z); o2.w = fmaf(p2.x, va.w, o2.w);
      o0.x = fmaf(p0.y, vb.x, o0.x); o0.y = fmaf(p0.y, vb.y, o0.y); o0.z = fmaf(p0.y, vb.z, o0.z); o0.w = fmaf(p0.y, vb.w, o0.w);
      o1.x = fmaf(p1.y, vb.x, o1.x); o1.y = fmaf(p1.y, vb.y, o1.y); o1.z = fmaf(p1.y, vb.z, o1.z); o1.w = fmaf(p1.y, vb.w, o1.w);
      o2.x = fmaf(p2.y, vb.x, o2.x); o2.y = fmaf(p2.y, vb.y, o2.y); o2.z = fmaf(p2.y, vb.z, o2.z); o2.w = fmaf(p2.y, vb.w, o2.w);
      o0.x = fmaf(p0.z, vc.x, o0.x); o0.y = fmaf(p0.z, vc.y, o0.y); o0.z = fmaf(p0.z, vc.z, o0.z); o0.w = fmaf(p0.z, vc.w, o0.w);
      o1.x = fmaf(p1.z, vc.x, o1.x); o1.y = fmaf(p1.z, vc.y, o1.y); o1.z = fmaf(p1.z, vc.z, o1.z); o1.w = fmaf(p1.z, vc.w, o1.w);
      o2.x = fmaf(p2.z, vc.x, o2.x); o2.y = fmaf(p2.z, vc.y, o2.y); o2.z = fmaf(p2.z, vc.z, o2.z); o2.w = fmaf(p2.z, vc.w, o2.w);
      o0.x = fmaf(p0.w, vd.x, o0.x); o0.y = fmaf(p0.w, vd.y, o0.y); o0.z = fmaf(p0.w, vd.z, o0.z); o0.w = fmaf(p0.w, vd.w, o0.w);
      o1.x = fmaf(p1.w, vd.x, o1.x); o1.y = fmaf(p1.w, vd.y, o1.y); o1.z = fmaf(p1.w, vd.z, o1.z); o1.w = fmaf(p1.w, vd.w, o1.w);
      o2.x = fmaf(p2.w, vd.x, o2.x); o2.y = fmaf(p2.w, vd.y, o2.y); o2.z = fmaf(p2.w, vd.z, o2.z); o2.w = fmaf(p2.w, vd.w, o2.w);
    }
    float4* pO4 = (float4*)pO;
    int obase = ((bh * NC + chunk) * Uc) * 16 + tx;
    pO4[obase + ty * 16] = o0;
    pO4[obase + (ty + 16) * 16] = o1;
    if (ty < 13) pO4[obase + (ty + 32) * 16] = o2;
  }
}

// Exact merge of chunk partials; out[b][t][h][d].
// One block per (bh,t) = 720 blocks. Thread (cg,d): cg=tid>>6 covers NC/4
// chunks, d=tid&63 one output dim. 2-sync LDS combine.
template<int NC>
__global__ __launch_bounds__(256) void k_merge(const float* __restrict__ pO, const float* __restrict__ pM,
                                               const float* __restrict__ pL, float* __restrict__ out) {
  constexpr int CPT = NC / 4;          // chunks per thread-group
  __shared__ float smax[4];
  __shared__ float sden[4];
  __shared__ float snum[4][64];
  int bid = blockIdx.x;                // 720 = 45*16, bid = t*16 + bh
  int bh = bid & 15, t = bid >> 4;
  int b = bh >> 3, h = bh & 7;
  int tid = threadIdx.x;
  int d = tid & 63, cg = tid >> 6;
  int mlbase = bh * NC * Uc + t;       // pM/pL index: + c*Uc
  float lm = -INFINITY;
  #pragma unroll 4
  for (int c = cg * CPT; c < (cg + 1) * CPT; ++c)
    lm = fmaxf(lm, pM[mlbase + c * Uc]);
  if (d == 0) smax[cg] = lm;
  __syncthreads();
  float m = fmaxf(fmaxf(smax[0], smax[1]), fmaxf(smax[2], smax[3]));
  float den = 0.f, num = 0.f;
  #pragma unroll 4
  for (int c = cg * CPT; c < (cg + 1) * CPT; ++c) {
    float mc = pM[mlbase + c * Uc];
    float wgt = (mc == -INFINITY) ? 0.f : __expf(mc - m);
    den += wgt * pL[mlbase + c * Uc];
    num += wgt * pO[(mlbase + c * Uc) * 64 + d];
  }
  if (d == 0) sden[cg] = den;
  snum[cg][d] = num;
  __syncthreads();
  if (cg == 0) {
    float dn = sden[0] + sden[1] + sden[2] + sden[3];
    float nm = snum[0][d] + snum[1][d] + snum[2][d] + snum[3][d];
    out[((b * Uc + t) * Hc + h) * 64 + d] = nm / dn;
  }
}

extern "C" void kernel_launch(void* const* d_in, const int* in_sizes, int n_in,
                              void* d_out, int out_size, void* d_ws, size_t ws_size,
                              hipStream_t stream) {
  const float* Q = (const float*)d_in[0];
  const float* K = (const float*)d_in[1];
  const float* V = (const float*)d_in[2];
  const int* amask = (const int*)d_in[3];
  float* out = (float*)d_out;
  char* ws = (char*)d_ws;
  float* M    = (float*)(ws + 0x000000);   // 65536 floats (256 KB)
  int*   topk = (int*)(ws + 0x040000);     // 720 ints
  float* qg   = (float*)(ws + 0x041000);   // 16*45*64 floats (184,320 B)
  float* pM   = (float*)(ws + 0x070000);
  // ws_size is constant across calls -> branch is deterministic (graph-safe).
  size_t need64 = 0x70000UL + 64UL * 190080UL;   // pM+pL+pO for NC=64 (~12.6 MB)
  size_t need32 = 0x70000UL + 32UL * 190080UL;
  int NC = ws_size >= need64 ? 64 : (ws_size >= need32 ? 32 : 16);
  float* pL = pM + 16 * NC * Uc;
  float* pO = pL + 16 * NC * Uc;

  k_scoreM<<<4096, 256, 0, stream>>>(Q, K, M);
  k_topk<<<BHc, 256, 0, stream>>>(M, Q, topk, qg);
  if (NC == 64) {
    k_attn<64><<<dim3(64, BHc), 256, 0, stream>>>(qg, K, V, amask, pO, pM, pL);
    k_merge<64><<<BHc * Uc, 256, 0, stream>>>(pO, pM, pL, out);
  } else if (NC == 32) {
    k_attn<32><<<dim3(32, BHc), 256, 0, stream>>>(qg, K, V, amask, pO, pM, pL);
    k_merge<32><<<BHc * Uc, 256, 0, stream>>>(pO, pM, pL, out);
  } else {
    k_attn<16><<<dim3(16, BHc), 256, 0, stream>>>(qg, K, V, amask, pO, pM, pL);
    k_merge<16><<<BHc * Uc, 256, 0, stream>>>(pO, pM, pL, out);
  }
}